// Round 1
// baseline (2287.163 us; speedup 1.0000x reference)
//
#include <hip/hip_runtime.h>

#define D_CODES 2048
#define C_DIM   256
#define MOM     0.99f
#define ONE_M   0.01f
#define EPSI    1e-5f

// output offsets (floats)
#define Q_OFF    0
#define LOSS_OFF 16777216
#define IDS_OFF  16777217
#define NE_OFF   16842753
#define NCS_OFF  17367041
#define NEA_OFF  17369089

// workspace offsets (floats)
#define WS_COUNTS 0
#define WS_ESUM   2048
#define WS_LOSSP  526336
#define WS_NTOT   527360
#define WS_NORMS  527361
#define WS_ZERO_N 527361

__global__ __launch_bounds__(256) void k_zero(float* __restrict__ ws) {
    int i = blockIdx.x * 256 + threadIdx.x;
    if (i < WS_ZERO_N) ws[i] = 0.f;
}

// one wave per embed row: |embed_d|^2
__global__ __launch_bounds__(256) void k_norms(const float* __restrict__ embed,
                                               float* __restrict__ norms) {
    int row  = blockIdx.x * 4 + (threadIdx.x >> 6);
    int lane = threadIdx.x & 63;
    float4 v = *(const float4*)(embed + (size_t)row * C_DIM + lane * 4);
    float s = v.x * v.x + v.y * v.y + v.z * v.z + v.w * v.w;
    #pragma unroll
    for (int o = 32; o; o >>= 1) s += __shfl_down(s, o);
    if (lane == 0) norms[row] = s;
}

// block = 64 pixels (fixed bi,hi; wi=0..63), 4 waves each scan 512 codes
__global__ __launch_bounds__(256) void k_main(
    const float* __restrict__ x, const float* __restrict__ embed,
    const float* __restrict__ norms, float* __restrict__ out,
    float* __restrict__ counts, float* __restrict__ esum,
    float* __restrict__ lossp)
{
    __shared__ float xs[C_DIM][64];   // [ch][wi], 64 KB
    const int t   = threadIdx.x;
    const int blk = blockIdx.x;
    const int bi  = blk >> 6;
    const int hi  = blk & 63;
    const float* xbase = x + (((size_t)bi * C_DIM) * 64 + hi) * 64; // + ch*4096 + wi

    // load x tile, coalesced float4 along wi
    {
        const int wi0 = (t & 15) << 2;
        const int ch0 = t >> 4;
        #pragma unroll
        for (int k = 0; k < 16; ++k) {
            int ch = ch0 + (k << 4);
            float4 v = *(const float4*)(xbase + (size_t)ch * 4096 + wi0);
            *(float4*)&xs[ch][wi0] = v;
        }
    }
    __syncthreads();

    const int lane = t & 63;                                   // = wi (pixel)
    const int wv   = __builtin_amdgcn_readfirstlane(t >> 6);   // wave id, SGPR
    float best = -3.4e38f;
    int bestd  = 0;
    const float* eb = embed + (size_t)wv * 512 * C_DIM;
    const float* nb = norms + wv * 512;

    for (int d0 = 0; d0 < 512; d0 += 8) {
        const float* e0 = eb + (size_t)d0 * C_DIM;
        float a0 = 0.f, a1 = 0.f, a2 = 0.f, a3 = 0.f;
        float a4 = 0.f, a5 = 0.f, a6 = 0.f, a7 = 0.f;
        #pragma unroll 8
        for (int ch = 0; ch < C_DIM; ++ch) {
            float xv = xs[ch][lane];
            a0 += xv * e0[ch];
            a1 += xv * e0[1 * C_DIM + ch];
            a2 += xv * e0[2 * C_DIM + ch];
            a3 += xv * e0[3 * C_DIM + ch];
            a4 += xv * e0[4 * C_DIM + ch];
            a5 += xv * e0[5 * C_DIM + ch];
            a6 += xv * e0[6 * C_DIM + ch];
            a7 += xv * e0[7 * C_DIM + ch];
        }
        const int db = wv * 512 + d0;
        float s;
        s = 2.f * a0 - nb[d0 + 0]; if (s > best) { best = s; bestd = db + 0; }
        s = 2.f * a1 - nb[d0 + 1]; if (s > best) { best = s; bestd = db + 1; }
        s = 2.f * a2 - nb[d0 + 2]; if (s > best) { best = s; bestd = db + 2; }
        s = 2.f * a3 - nb[d0 + 3]; if (s > best) { best = s; bestd = db + 3; }
        s = 2.f * a4 - nb[d0 + 4]; if (s > best) { best = s; bestd = db + 4; }
        s = 2.f * a5 - nb[d0 + 5]; if (s > best) { best = s; bestd = db + 5; }
        s = 2.f * a6 - nb[d0 + 6]; if (s > best) { best = s; bestd = db + 6; }
        s = 2.f * a7 - nb[d0 + 7]; if (s > best) { best = s; bestd = db + 7; }
    }
    __syncthreads();

    // cross-wave argmax reduce; alias scratch into xs rows 0..8 (ch<9 re-read from global later)
    float* red = &xs[0][0];
    int*  redi = (int*)red;
    red[(wv << 6) + lane] = best;
    redi[256 + (wv << 6) + lane] = bestd;
    __syncthreads();
    if (t < 64) {
        float b = red[t];
        int  bd = redi[256 + t];
        #pragma unroll
        for (int w = 1; w < 4; ++w) {
            float s = red[(w << 6) + t];
            int  sd = redi[256 + (w << 6) + t];
            if (s > b || (s == b && sd < bd)) { b = s; bd = sd; }
        }
        redi[512 + t] = bd;
        out[IDS_OFF + ((size_t)bi << 12) + (t << 6) + hi] = (float)bd;  // n = bi*4096 + wi*64 + hi
        atomicAdd(&counts[bd], 1.0f);
    }
    __syncthreads();

    // quantized write + commit-loss partial + embed_sum scatter
    const int idp = redi[512 + lane];
    float lsum = 0.f;
    for (int k = 0; k < 64; ++k) {
        int ch = wv + (k << 2);
        float q  = embed[(size_t)idp * C_DIM + ch];
        float xv = (ch < 9) ? xbase[(size_t)ch * 4096 + lane] : xs[ch][lane];
        out[Q_OFF + (((size_t)(bi * C_DIM + ch)) * 64 + hi) * 64 + lane] = q;
        float d = xv - q;
        lsum += d * d;
        atomicAdd(&esum[(size_t)ch * D_CODES + idp], xv);
    }
    #pragma unroll
    for (int o = 32; o; o >>= 1) lsum += __shfl_down(lsum, o);
    __syncthreads();
    if (lane == 0) red[wv] = lsum;
    __syncthreads();
    if (t == 0) lossp[blk] = red[0] + red[1] + red[2] + red[3];
}

// single block: loss finalize + new_cluster_size + n_tot
__global__ __launch_bounds__(256) void k_final_small(
    const float* __restrict__ cs_in, const float* __restrict__ counts,
    const float* __restrict__ lossp, float* __restrict__ out,
    float* __restrict__ ntot)
{
    __shared__ float sm[256];
    const int t = threadIdx.x;
    float s = 0.f;
    for (int i = t; i < 1024; i += 256) s += lossp[i];
    sm[t] = s; __syncthreads();
    for (int o = 128; o; o >>= 1) { if (t < o) sm[t] += sm[t + o]; __syncthreads(); }
    if (t == 0) out[LOSS_OFF] = sm[0] / 16777216.f;
    __syncthreads();
    float cs = 0.f;
    for (int i = t; i < D_CODES; i += 256) {
        float v = MOM * cs_in[i] + ONE_M * counts[i];
        out[NCS_OFF + i] = v;
        cs += v;
    }
    sm[t] = cs; __syncthreads();
    for (int o = 128; o; o >>= 1) { if (t < o) sm[t] += sm[t + o]; __syncthreads(); }
    if (t == 0) *ntot = sm[0];
}

// new_embed_avg + new_embed
__global__ __launch_bounds__(256) void k_final_embed(
    const float* __restrict__ embed_avg, const float* __restrict__ esum,
    const float* __restrict__ ntotp, float* __restrict__ out)
{
    int b  = blockIdx.x;
    int ch = b >> 3;
    int d  = ((b & 7) << 8) + threadIdx.x;
    float ntot = *ntotp;
    float ncs  = out[NCS_OFF + d];
    float csm  = ntot * (ncs + EPSI) / (ntot + (float)D_CODES * EPSI);
    size_t i = (size_t)ch * D_CODES + d;
    float nea = MOM * embed_avg[i] + ONE_M * esum[i];
    out[NEA_OFF + i] = nea;
    out[NE_OFF + (size_t)d * C_DIM + ch] = nea / csm;
}

extern "C" void kernel_launch(void* const* d_in, const int* in_sizes, int n_in,
                              void* d_out, int out_size, void* d_ws, size_t ws_size,
                              hipStream_t stream) {
    const float* x     = (const float*)d_in[0];
    const float* embed = (const float*)d_in[1];
    const float* cs    = (const float*)d_in[2];
    const float* ea    = (const float*)d_in[3];
    float* out = (float*)d_out;
    float* ws  = (float*)d_ws;
    float* counts = ws + WS_COUNTS;
    float* esum   = ws + WS_ESUM;
    float* lossp  = ws + WS_LOSSP;
    float* ntot   = ws + WS_NTOT;
    float* norms  = ws + WS_NORMS;

    k_zero<<<(WS_ZERO_N + 255) / 256, 256, 0, stream>>>(ws);
    k_norms<<<512, 256, 0, stream>>>(embed, norms);
    k_main<<<1024, 256, 0, stream>>>(x, embed, norms, out, counts, esum, lossp);
    k_final_small<<<1, 256, 0, stream>>>(cs, counts, lossp, out, ntot);
    k_final_embed<<<2048, 256, 0, stream>>>(ea, esum, ntot, out);
}

// Round 2
// 1167.125 us; speedup vs baseline: 1.9597x; 1.9597x over previous
//
#include <hip/hip_runtime.h>

#define D_CODES 2048
#define C_DIM   256
#define MOM     0.99f
#define ONE_M   0.01f
#define EPSI    1e-5f
#define TAU     0.0625f
#define RCAP    32768

// output offsets (floats)
#define Q_OFF    0
#define LOSS_OFF 16777216
#define IDS_OFF  16777217
#define NE_OFF   16842753
#define NCS_OFF  17367041
#define NEA_OFF  17369089

// workspace offsets (floats)
#define WS_COUNTS 0
#define WS_ESUM   2048
#define WS_LOSSP  526336
#define WS_NTOT   527360
#define WS_RCNT   527361
#define WS_NORMS  527364
#define WS_RLIST  529412
#define WS_E2     562180
#define WS_ZERO_N 527362

typedef __attribute__((ext_vector_type(8))) short short8;
typedef __attribute__((ext_vector_type(4))) float f32x4;

__device__ __forceinline__ unsigned short f2bf(float v) {
    unsigned u = __float_as_uint(v);
    unsigned r = u + 0x7FFFu + ((u >> 16) & 1u);
    return (unsigned short)(r >> 16);
}
__device__ __forceinline__ float bf2f(unsigned short h) {
    return __uint_as_float(((unsigned)h) << 16);
}
__device__ __forceinline__ f32x4 MF(short8 a, short8 b, f32x4 c) {
    return __builtin_amdgcn_mfma_f32_16x16x32_bf16(a, b, c, 0, 0, 0);
}

__global__ __launch_bounds__(256) void k_zero(float* __restrict__ ws) {
    int i = blockIdx.x * 256 + threadIdx.x;
    if (i < WS_ZERO_N) ws[i] = 0.f;
}

__global__ __launch_bounds__(256) void k_norms(const float* __restrict__ embed,
                                               float* __restrict__ norms) {
    int row  = blockIdx.x * 4 + (threadIdx.x >> 6);
    int lane = threadIdx.x & 63;
    float4 v = *(const float4*)(embed + (size_t)row * C_DIM + lane * 4);
    float s = v.x * v.x + v.y * v.y + v.z * v.z + v.w * v.w;
    #pragma unroll
    for (int o = 32; o; o >>= 1) s += __shfl_down(s, o);
    if (lane == 0) norms[row] = s;
}

// pack embed into MFMA A-fragment order, bf16 hi/lo, 64 stages x 32 codes
// slot (s, r, kc, p, l): 16B = embed[s*32+r*16+(l&15)][kc*32+(l>>4)*8 .. +7]
__global__ __launch_bounds__(256) void k_eprep(const float* __restrict__ embed,
                                               float* __restrict__ e2f) {
    int s = blockIdx.x, t = threadIdx.x;
    char* e2 = (char*)e2f;
    #pragma unroll
    for (int it = 0; it < 4; ++it) {
        int u = it * 256 + t;                  // 0..1023 = (r, kc, l)
        int r = u >> 9, kc = (u >> 6) & 7, l = u & 63;
        int code = s * 32 + r * 16 + (l & 15);
        int ch0  = kc * 32 + ((l >> 4) << 3);
        const float* src = embed + (size_t)code * C_DIM + ch0;
        float4 v0 = *(const float4*)src;
        float4 v1 = *(const float4*)(src + 4);
        float vv[8] = {v0.x, v0.y, v0.z, v0.w, v1.x, v1.y, v1.z, v1.w};
        short8 hi, lo;
        #pragma unroll
        for (int j = 0; j < 8; ++j) {
            unsigned short h = f2bf(vv[j]);
            hi[j] = (short)h;
            lo[j] = (short)f2bf(vv[j] - bf2f(h));
        }
        char* dst = e2 + (size_t)s * 32768 + (size_t)(((r * 8 + kc) * 2 + 0) * 64 + l) * 16;
        *(short8*)dst = hi;
        *(short8*)(dst + 1024) = lo;           // p=1 slot
    }
}

__device__ __forceinline__ void stage_copy(const char* __restrict__ g, char* lds_base,
                                           int w, int l) {
    // 32 KB per stage; wave w copies bytes [w*8192, w*8192+8192)
    #pragma unroll
    for (int i = 0; i < 8; ++i) {
        int off = w * 8192 + i * 1024;
        __builtin_amdgcn_global_load_lds(
            (const __attribute__((address_space(1))) void*)(g + off + l * 16),
            (__attribute__((address_space(3))) void*)(lds_base + off),
            16, 0, 0);
    }
}

// block b: bi = b>>5, hi-pair {2q, 2q+1}, q = b&31. 128 pixels/block.
// wave w: 32 pixels: hi = 2q + (w>>1), wi = (w&1)*32 + nt*16 + (l&15), nt in {0,1}
__global__ __launch_bounds__(256, 2) void k_main(
    const float* __restrict__ x, const float* __restrict__ e2f,
    const float* __restrict__ norms, float* __restrict__ out,
    unsigned* __restrict__ rcnt, int* __restrict__ rlist)
{
    __shared__ char smem[65536];
    const int t  = threadIdx.x;
    const int l  = t & 63;
    const int w  = __builtin_amdgcn_readfirstlane(t >> 6);
    const int bi = blockIdx.x >> 5;
    const int q  = blockIdx.x & 31;
    const char* e2 = (const char*)e2f;

    // ---- prologue: build x B-fragments (hi/lo) in registers ----
    short8 bxh[2][8], bxl[2][8];
    {
        float* xs = (float*)smem;              // [chl 64][hiq 2][wi 64] fp32 = 32 KB
        const int hiq = w >> 1;
        const int wib = (w & 1) * 32;
        for (int c = 0; c < 4; ++c) {
            __syncthreads();
            #pragma unroll
            for (int k = 0; k < 8; ++k) {
                int fidx = (k * 256 + t) * 4;
                int chl = fidx >> 7, rem = fidx & 127;
                int hq = rem >> 6, wi0 = rem & 63;
                float4 v = *(const float4*)(x + (((size_t)(bi * C_DIM + c * 64 + chl)) * 64
                                                 + 2 * q + hq) * 64 + wi0);
                *(float4*)&xs[fidx] = v;
            }
            __syncthreads();
            #pragma unroll
            for (int kcl = 0; kcl < 2; ++kcl) {
                #pragma unroll
                for (int nt = 0; nt < 2; ++nt) {
                    short8 hi, lo;
                    #pragma unroll
                    for (int j = 0; j < 8; ++j) {
                        int chl = kcl * 32 + ((l >> 4) << 3) + j;
                        float v = xs[chl * 128 + hiq * 64 + wib + nt * 16 + (l & 15)];
                        unsigned short h = f2bf(v);
                        hi[j] = (short)h;
                        lo[j] = (short)f2bf(v - bf2f(h));
                    }
                    bxh[nt][c * 2 + kcl] = hi;
                    bxl[nt][c * 2 + kcl] = lo;
                }
            }
        }
        __syncthreads();
    }

    // ---- main loop: 64 stages of 32 codes, double-buffered LDS ----
    float m1[2] = {-3.4e38f, -3.4e38f}, m2[2] = {-3.4e38f, -3.4e38f};
    int   i1[2] = {0, 0};

    stage_copy(e2, smem, w, l);
    __syncthreads();

    for (int s = 0; s < 64; ++s) {
        char* cur = smem + (s & 1) * 32768;
        if (s < 63)
            stage_copy(e2 + (size_t)(s + 1) * 32768, smem + ((s + 1) & 1) * 32768, w, l);

        #pragma unroll
        for (int r = 0; r < 2; ++r) {
            f32x4 z = {0.f, 0.f, 0.f, 0.f};
            f32x4 hh0 = z, hl0 = z, lh0 = z, hh1 = z, hl1 = z, lh1 = z;
            #pragma unroll
            for (int kc = 0; kc < 8; ++kc) {
                short8 ah = *(const short8*)(cur + ((r * 8 + kc) * 2 + 0) * 1024 + l * 16);
                short8 al = *(const short8*)(cur + ((r * 8 + kc) * 2 + 1) * 1024 + l * 16);
                hh0 = MF(ah, bxh[0][kc], hh0);
                hl0 = MF(ah, bxl[0][kc], hl0);
                lh0 = MF(al, bxh[0][kc], lh0);
                hh1 = MF(ah, bxh[1][kc], hh1);
                hl1 = MF(ah, bxl[1][kc], hl1);
                lh1 = MF(al, bxh[1][kc], lh1);
            }
            int c0 = s * 32 + r * 16 + ((l >> 4) << 2);
            float4 nrm = *(const float4*)(norms + c0);
            float nr[4] = {nrm.x, nrm.y, nrm.z, nrm.w};
            #pragma unroll
            for (int reg = 0; reg < 4; ++reg) {
                float s0 = 2.f * (hh0[reg] + hl0[reg] + lh0[reg]) - nr[reg];
                float s1 = 2.f * (hh1[reg] + hl1[reg] + lh1[reg]) - nr[reg];
                int code = c0 + reg;
                if (s0 > m1[0]) { m2[0] = m1[0]; m1[0] = s0; i1[0] = code; }
                else            { m2[0] = fmaxf(m2[0], s0); }
                if (s1 > m1[1]) { m2[1] = m1[1]; m1[1] = s1; i1[1] = code; }
                else            { m2[1] = fmaxf(m2[1], s1); }
            }
        }
        __syncthreads();
    }

    // ---- cross-lane reduce over the 4 row-groups ----
    #pragma unroll
    for (int nt = 0; nt < 2; ++nt) {
        float a1 = m1[nt], a2 = m2[nt];
        int   ai = i1[nt];
        #pragma unroll
        for (int off = 16; off <= 32; off <<= 1) {
            float o1 = __shfl_xor(a1, off);
            int   oi = __shfl_xor(ai, off);
            float o2 = __shfl_xor(a2, off);
            if (o1 > a1)       { a2 = fmaxf(a1, o2); a1 = o1; ai = oi; }
            else if (o1 == a1) { if (oi < ai) ai = oi; a2 = a1; }
            else               { a2 = fmaxf(a2, o1); }
        }
        if (l < 16) {
            int wi = (w & 1) * 32 + nt * 16 + l;
            int hi_ = 2 * q + (w >> 1);
            int n = (bi << 12) + (wi << 6) + hi_;
            out[IDS_OFF + n] = (float)ai;
            if (a1 - a2 < TAU) {
                unsigned j = atomicAdd(rcnt, 1u);
                if (j < RCAP) rlist[j] = n;
            }
        }
    }
}

// exact fp32 rescore for flagged (near-tie) pixels
__global__ __launch_bounds__(256) void k_rescue(
    const float* __restrict__ x, const float* __restrict__ embed,
    const float* __restrict__ norms, const unsigned* __restrict__ rcnt,
    const int* __restrict__ rlist, float* __restrict__ out)
{
    __shared__ float xs_s[256];
    __shared__ float rs[256];
    __shared__ int   ri[256];
    const int t = threadIdx.x;
    int nf = (int)min(*rcnt, (unsigned)RCAP);
    for (int idx = blockIdx.x; idx < nf; idx += gridDim.x) {
        int n = rlist[idx];
        int bi = n >> 12, wi = (n >> 6) & 63, hi = n & 63;
        xs_s[t] = x[(((size_t)(bi * C_DIM + t)) * 64 + hi) * 64 + wi];
        __syncthreads();
        float best = -3.4e38f; int bd = 0;
        for (int d = t; d < D_CODES; d += 256) {
            const float* er = embed + (size_t)d * C_DIM;
            float a0 = 0.f, a1 = 0.f, a2 = 0.f, a3 = 0.f;
            for (int c = 0; c < C_DIM; c += 4) {
                float4 e4 = *(const float4*)(er + c);
                a0 += xs_s[c]     * e4.x;
                a1 += xs_s[c + 1] * e4.y;
                a2 += xs_s[c + 2] * e4.z;
                a3 += xs_s[c + 3] * e4.w;
            }
            float s = 2.f * (a0 + a1 + a2 + a3) - norms[d];
            if (s > best) { best = s; bd = d; }
        }
        rs[t] = best; ri[t] = bd;
        __syncthreads();
        for (int o = 128; o; o >>= 1) {
            if (t < o) {
                if (rs[t + o] > rs[t] || (rs[t + o] == rs[t] && ri[t + o] < ri[t])) {
                    rs[t] = rs[t + o]; ri[t] = ri[t + o];
                }
            }
            __syncthreads();
        }
        if (t == 0) out[IDS_OFF + n] = (float)ri[0];
        __syncthreads();
    }
}

// quantized + commit-loss partials + counts + esum (exact fp32 from final ids)
__global__ __launch_bounds__(256) void k_stats(
    const float* __restrict__ x, const float* __restrict__ embed,
    float* __restrict__ out, float* __restrict__ counts,
    float* __restrict__ esum, float* __restrict__ lossp)
{
    __shared__ int   ids_s[64];
    __shared__ float red[4];
    const int t = threadIdx.x;
    const int blk = blockIdx.x;
    const int bi = blk >> 6;
    const int hi = blk & 63;
    if (t < 64) ids_s[t] = (int)out[IDS_OFF + ((size_t)bi << 12) + (t << 6) + hi];
    __syncthreads();
    const int w = t >> 6, lane = t & 63;
    const float* xb = x + (((size_t)bi * C_DIM) * 64 + hi) * 64;   // + ch*4096 + wi
    const int idp = ids_s[lane];
    float lsum = 0.f;
    for (int k = 0; k < 64; ++k) {
        int ch = w + (k << 2);
        float xv = xb[(size_t)ch * 4096 + lane];
        float qv = embed[(size_t)idp * C_DIM + ch];
        out[Q_OFF + (((size_t)(bi * C_DIM + ch)) * 64 + hi) * 64 + lane] = qv;
        float d = xv - qv;
        lsum += d * d;
        atomicAdd(&esum[(size_t)ch * D_CODES + idp], xv);
    }
    #pragma unroll
    for (int o = 32; o; o >>= 1) lsum += __shfl_down(lsum, o);
    if (lane == 0) red[w] = lsum;
    __syncthreads();
    if (t == 0) lossp[blk] = red[0] + red[1] + red[2] + red[3];
    if (t < 64) atomicAdd(&counts[ids_s[t]], 1.0f);
}

__global__ __launch_bounds__(256) void k_final_small(
    const float* __restrict__ cs_in, const float* __restrict__ counts,
    const float* __restrict__ lossp, float* __restrict__ out,
    float* __restrict__ ntot)
{
    __shared__ float sm[256];
    const int t = threadIdx.x;
    float s = 0.f;
    for (int i = t; i < 1024; i += 256) s += lossp[i];
    sm[t] = s; __syncthreads();
    for (int o = 128; o; o >>= 1) { if (t < o) sm[t] += sm[t + o]; __syncthreads(); }
    if (t == 0) out[LOSS_OFF] = sm[0] / 16777216.f;
    __syncthreads();
    float cs = 0.f;
    for (int i = t; i < D_CODES; i += 256) {
        float v = MOM * cs_in[i] + ONE_M * counts[i];
        out[NCS_OFF + i] = v;
        cs += v;
    }
    sm[t] = cs; __syncthreads();
    for (int o = 128; o; o >>= 1) { if (t < o) sm[t] += sm[t + o]; __syncthreads(); }
    if (t == 0) *ntot = sm[0];
}

__global__ __launch_bounds__(256) void k_final_embed(
    const float* __restrict__ embed_avg, const float* __restrict__ esum,
    const float* __restrict__ ntotp, float* __restrict__ out)
{
    int b  = blockIdx.x;
    int ch = b >> 3;
    int d  = ((b & 7) << 8) + threadIdx.x;
    float ntot = *ntotp;
    float ncs  = out[NCS_OFF + d];
    float csm  = ntot * (ncs + EPSI) / (ntot + (float)D_CODES * EPSI);
    size_t i = (size_t)ch * D_CODES + d;
    float nea = MOM * embed_avg[i] + ONE_M * esum[i];
    out[NEA_OFF + i] = nea;
    out[NE_OFF + (size_t)d * C_DIM + ch] = nea / csm;
}

extern "C" void kernel_launch(void* const* d_in, const int* in_sizes, int n_in,
                              void* d_out, int out_size, void* d_ws, size_t ws_size,
                              hipStream_t stream) {
    const float* x     = (const float*)d_in[0];
    const float* embed = (const float*)d_in[1];
    const float* cs    = (const float*)d_in[2];
    const float* ea    = (const float*)d_in[3];
    float* out = (float*)d_out;
    float* ws  = (float*)d_ws;
    float*    counts = ws + WS_COUNTS;
    float*    esum   = ws + WS_ESUM;
    float*    lossp  = ws + WS_LOSSP;
    float*    ntot   = ws + WS_NTOT;
    unsigned* rcnt   = (unsigned*)(ws + WS_RCNT);
    float*    norms  = ws + WS_NORMS;
    int*      rlist  = (int*)(ws + WS_RLIST);
    float*    e2     = ws + WS_E2;

    k_zero<<<(WS_ZERO_N + 255) / 256, 256, 0, stream>>>(ws);
    k_norms<<<512, 256, 0, stream>>>(embed, norms);
    k_eprep<<<64, 256, 0, stream>>>(embed, e2);
    k_main<<<512, 256, 0, stream>>>(x, e2, norms, out, rcnt, rlist);
    k_rescue<<<128, 256, 0, stream>>>(x, embed, norms, rcnt, rlist, out);
    k_stats<<<1024, 256, 0, stream>>>(x, embed, out, counts, esum, lossp);
    k_final_small<<<1, 256, 0, stream>>>(cs, counts, lossp, out, ntot);
    k_final_embed<<<2048, 256, 0, stream>>>(ea, esum, ntot, out);
}

// Round 3
// 768.560 us; speedup vs baseline: 2.9759x; 1.5186x over previous
//
#include <hip/hip_runtime.h>

#define D_CODES 2048
#define C_DIM   256
#define MOM     0.99f
#define ONE_M   0.01f
#define EPSI    1e-5f
#define TAU     0.0625f
#define RCAP    16384

// output offsets (floats)
#define Q_OFF    0
#define LOSS_OFF 16777216
#define IDS_OFF  16777217
#define NE_OFF   16842753
#define NCS_OFF  17367041
#define NEA_OFF  17369089

// workspace offsets (floats)
#define WS_ICNT   0
#define WS_CNTF   2048
#define WS_OFFS   4096
#define WS_CURS   6144
#define WS_LOSSD  8192
#define WS_SUMX2  10240
#define WS_NTOT   11264
#define WS_RCNT   11268
#define WS_NORMS  11272
#define WS_RLIST  13320
#define WS_ESUM   29704
#define WS_E2     553992

typedef __attribute__((ext_vector_type(8))) short short8;
typedef __attribute__((ext_vector_type(4))) float f32x4;

__device__ __forceinline__ unsigned short f2bf(float v) {
    unsigned u = __float_as_uint(v);
    unsigned r = u + 0x7FFFu + ((u >> 16) & 1u);
    return (unsigned short)(r >> 16);
}
__device__ __forceinline__ float bf2f(unsigned short h) {
    return __uint_as_float(((unsigned)h) << 16);
}
__device__ __forceinline__ f32x4 MF(short8 a, short8 b, f32x4 c) {
    return __builtin_amdgcn_mfma_f32_16x16x32_bf16(a, b, c, 0, 0, 0);
}

__global__ __launch_bounds__(256) void k_zero(int* __restrict__ icnt,
                                              unsigned* __restrict__ rcnt) {
    int i = blockIdx.x * 256 + threadIdx.x;
    if (i < D_CODES) icnt[i] = 0;
    if (i == 0) *rcnt = 0u;
}

__global__ __launch_bounds__(256) void k_norms(const float* __restrict__ embed,
                                               float* __restrict__ norms) {
    int row  = blockIdx.x * 4 + (threadIdx.x >> 6);
    int lane = threadIdx.x & 63;
    float4 v = *(const float4*)(embed + (size_t)row * C_DIM + lane * 4);
    float s = v.x * v.x + v.y * v.y + v.z * v.z + v.w * v.w;
    #pragma unroll
    for (int o = 32; o; o >>= 1) s += __shfl_down(s, o);
    if (lane == 0) norms[row] = s;
}

// pack embed into MFMA A-fragment order, bf16 hi/lo, 64 stages x 32 codes
__global__ __launch_bounds__(256) void k_eprep(const float* __restrict__ embed,
                                               float* __restrict__ e2f) {
    int s = blockIdx.x, t = threadIdx.x;
    char* e2 = (char*)e2f;
    #pragma unroll
    for (int it = 0; it < 4; ++it) {
        int u = it * 256 + t;
        int r = u >> 9, kc = (u >> 6) & 7, l = u & 63;
        int code = s * 32 + r * 16 + (l & 15);
        int ch0  = kc * 32 + ((l >> 4) << 3);
        const float* src = embed + (size_t)code * C_DIM + ch0;
        float4 v0 = *(const float4*)src;
        float4 v1 = *(const float4*)(src + 4);
        float vv[8] = {v0.x, v0.y, v0.z, v0.w, v1.x, v1.y, v1.z, v1.w};
        short8 hi, lo;
        #pragma unroll
        for (int j = 0; j < 8; ++j) {
            unsigned short h = f2bf(vv[j]);
            hi[j] = (short)h;
            lo[j] = (short)f2bf(vv[j] - bf2f(h));
        }
        char* dst = e2 + (size_t)s * 32768 + (size_t)(((r * 8 + kc) * 2 + 0) * 64 + l) * 16;
        *(short8*)dst = hi;
        *(short8*)(dst + 1024) = lo;
    }
}

// transpose x -> xt[n][ch] (into out's quantized region, overwritten later) + sum x^2
__global__ __launch_bounds__(256) void k_xt(const float* __restrict__ x,
                                            float* __restrict__ xt,
                                            float* __restrict__ sumx2p) {
    __shared__ float xs2[32][257];
    __shared__ float wred[4];
    const int t = threadIdx.x;
    const int bi = blockIdx.x >> 6;
    const int hi = blockIdx.x & 63;
    const int wl = t & 31;
    const int chh = t >> 5;            // 0..7
    float sx2 = 0.f;
    #pragma unroll
    for (int pass = 0; pass < 2; ++pass) {
        __syncthreads();
        #pragma unroll 8
        for (int k = 0; k < 32; ++k) {
            int ch = k * 8 + chh;
            float v = x[((size_t)(bi * C_DIM + ch)) * 4096 + hi * 64 + pass * 32 + wl];
            sx2 += v * v;
            xs2[wl][ch] = v;
        }
        __syncthreads();
        #pragma unroll 8
        for (int j = 0; j < 32; ++j) {
            int wi = pass * 32 + j;
            size_t n = (size_t)bi * 4096 + wi * 64 + hi;
            xt[n * C_DIM + t] = xs2[j][t];
        }
    }
    #pragma unroll
    for (int o = 32; o; o >>= 1) sx2 += __shfl_down(sx2, o);
    __syncthreads();
    if ((t & 63) == 0) wred[t >> 6] = sx2;
    __syncthreads();
    if (t == 0) sumx2p[blockIdx.x] = wred[0] + wred[1] + wred[2] + wred[3];
}

__device__ __forceinline__ void stage_copy(const char* __restrict__ g, char* lds_base,
                                           int w, int l) {
    #pragma unroll
    for (int i = 0; i < 8; ++i) {
        int off = w * 8192 + i * 1024;
        __builtin_amdgcn_global_load_lds(
            (const __attribute__((address_space(1))) void*)(g + off + l * 16),
            (__attribute__((address_space(3))) void*)(lds_base + off),
            16, 0, 0);
    }
}

// MFMA split-bf16 scores + per-pixel argmax (+near-tie flagging)
__global__ __launch_bounds__(256, 2) void k_main(
    const float* __restrict__ x, const float* __restrict__ e2f,
    const float* __restrict__ norms, float* __restrict__ out,
    unsigned* __restrict__ rcnt, int* __restrict__ rlist)
{
    __shared__ char smem[65536];
    const int t  = threadIdx.x;
    const int l  = t & 63;
    const int w  = __builtin_amdgcn_readfirstlane(t >> 6);
    const int bi = blockIdx.x >> 5;
    const int q  = blockIdx.x & 31;
    const char* e2 = (const char*)e2f;

    short8 bxh[2][8], bxl[2][8];
    {
        float* xs = (float*)smem;
        const int hiq = w >> 1;
        const int wib = (w & 1) * 32;
        for (int c = 0; c < 4; ++c) {
            __syncthreads();
            #pragma unroll
            for (int k = 0; k < 8; ++k) {
                int fidx = (k * 256 + t) * 4;
                int chl = fidx >> 7, rem = fidx & 127;
                int hq = rem >> 6, wi0 = rem & 63;
                float4 v = *(const float4*)(x + (((size_t)(bi * C_DIM + c * 64 + chl)) * 64
                                                 + 2 * q + hq) * 64 + wi0);
                *(float4*)&xs[fidx] = v;
            }
            __syncthreads();
            #pragma unroll
            for (int kcl = 0; kcl < 2; ++kcl) {
                #pragma unroll
                for (int nt = 0; nt < 2; ++nt) {
                    short8 hi, lo;
                    #pragma unroll
                    for (int j = 0; j < 8; ++j) {
                        int chl = kcl * 32 + ((l >> 4) << 3) + j;
                        float v = xs[chl * 128 + hiq * 64 + wib + nt * 16 + (l & 15)];
                        unsigned short h = f2bf(v);
                        hi[j] = (short)h;
                        lo[j] = (short)f2bf(v - bf2f(h));
                    }
                    bxh[nt][c * 2 + kcl] = hi;
                    bxl[nt][c * 2 + kcl] = lo;
                }
            }
        }
        __syncthreads();
    }

    float m1[2] = {-3.4e38f, -3.4e38f}, m2[2] = {-3.4e38f, -3.4e38f};
    int   i1[2] = {0, 0};

    stage_copy(e2, smem, w, l);
    __syncthreads();

    for (int s = 0; s < 64; ++s) {
        char* cur = smem + (s & 1) * 32768;
        if (s < 63)
            stage_copy(e2 + (size_t)(s + 1) * 32768, smem + ((s + 1) & 1) * 32768, w, l);

        #pragma unroll
        for (int r = 0; r < 2; ++r) {
            f32x4 z = {0.f, 0.f, 0.f, 0.f};
            f32x4 hh0 = z, hl0 = z, lh0 = z, hh1 = z, hl1 = z, lh1 = z;
            #pragma unroll
            for (int kc = 0; kc < 8; ++kc) {
                short8 ah = *(const short8*)(cur + ((r * 8 + kc) * 2 + 0) * 1024 + l * 16);
                short8 al = *(const short8*)(cur + ((r * 8 + kc) * 2 + 1) * 1024 + l * 16);
                hh0 = MF(ah, bxh[0][kc], hh0);
                hl0 = MF(ah, bxl[0][kc], hl0);
                lh0 = MF(al, bxh[0][kc], lh0);
                hh1 = MF(ah, bxh[1][kc], hh1);
                hl1 = MF(ah, bxl[1][kc], hl1);
                lh1 = MF(al, bxh[1][kc], lh1);
            }
            int c0 = s * 32 + r * 16 + ((l >> 4) << 2);
            float4 nrm = *(const float4*)(norms + c0);
            float nr[4] = {nrm.x, nrm.y, nrm.z, nrm.w};
            #pragma unroll
            for (int reg = 0; reg < 4; ++reg) {
                float s0 = 2.f * (hh0[reg] + hl0[reg] + lh0[reg]) - nr[reg];
                float s1 = 2.f * (hh1[reg] + hl1[reg] + lh1[reg]) - nr[reg];
                int code = c0 + reg;
                if (s0 > m1[0]) { m2[0] = m1[0]; m1[0] = s0; i1[0] = code; }
                else            { m2[0] = fmaxf(m2[0], s0); }
                if (s1 > m1[1]) { m2[1] = m1[1]; m1[1] = s1; i1[1] = code; }
                else            { m2[1] = fmaxf(m2[1], s1); }
            }
        }
        __syncthreads();
    }

    #pragma unroll
    for (int nt = 0; nt < 2; ++nt) {
        float a1 = m1[nt], a2 = m2[nt];
        int   ai = i1[nt];
        #pragma unroll
        for (int off = 16; off <= 32; off <<= 1) {
            float o1 = __shfl_xor(a1, off);
            int   oi = __shfl_xor(ai, off);
            float o2 = __shfl_xor(a2, off);
            if (o1 > a1)       { a2 = fmaxf(a1, o2); a1 = o1; ai = oi; }
            else if (o1 == a1) { if (oi < ai) ai = oi; a2 = a1; }
            else               { a2 = fmaxf(a2, o1); }
        }
        if (l < 16) {
            int wi = (w & 1) * 32 + nt * 16 + l;
            int hi_ = 2 * q + (w >> 1);
            int n = (bi << 12) + (wi << 6) + hi_;
            out[IDS_OFF + n] = (float)ai;
            if (a1 - a2 < TAU) {
                unsigned j = atomicAdd(rcnt, 1u);
                if (j < RCAP) rlist[j] = n;
            }
        }
    }
}

// exact fp32 rescore for flagged near-tie pixels
__global__ __launch_bounds__(256) void k_rescue(
    const float* __restrict__ x, const float* __restrict__ embed,
    const float* __restrict__ norms, const unsigned* __restrict__ rcnt,
    const int* __restrict__ rlist, float* __restrict__ out)
{
    __shared__ float xs_s[256];
    __shared__ float rs[256];
    __shared__ int   ri[256];
    const int t = threadIdx.x;
    int nf = (int)min(*rcnt, (unsigned)RCAP);
    for (int idx = blockIdx.x; idx < nf; idx += gridDim.x) {
        int n = rlist[idx];
        int bi = n >> 12, wi = (n >> 6) & 63, hi = n & 63;
        xs_s[t] = x[(((size_t)(bi * C_DIM + t)) * 64 + hi) * 64 + wi];
        __syncthreads();
        float best = -3.4e38f; int bd = 0;
        for (int d = t; d < D_CODES; d += 256) {
            const float* er = embed + (size_t)d * C_DIM;
            float a0 = 0.f, a1 = 0.f, a2 = 0.f, a3 = 0.f;
            for (int c = 0; c < C_DIM; c += 4) {
                float4 e4 = *(const float4*)(er + c);
                a0 += xs_s[c]     * e4.x;
                a1 += xs_s[c + 1] * e4.y;
                a2 += xs_s[c + 2] * e4.z;
                a3 += xs_s[c + 3] * e4.w;
            }
            float s = 2.f * (a0 + a1 + a2 + a3) - norms[d];
            if (s > best) { best = s; bd = d; }
        }
        rs[t] = best; ri[t] = bd;
        __syncthreads();
        for (int o = 128; o; o >>= 1) {
            if (t < o) {
                if (rs[t + o] > rs[t] || (rs[t + o] == rs[t] && ri[t + o] < ri[t])) {
                    rs[t] = rs[t + o]; ri[t] = ri[t + o];
                }
            }
            __syncthreads();
        }
        if (t == 0) out[IDS_OFF + n] = (float)ri[0];
        __syncthreads();
    }
}

__global__ __launch_bounds__(256) void k_hist(const float* __restrict__ out,
                                              int* __restrict__ icnt) {
    int n = blockIdx.x * 256 + threadIdx.x;
    int id = (int)out[IDS_OFF + n];
    atomicAdd(&icnt[id], 1);
}

__global__ __launch_bounds__(256) void k_prefix(const int* __restrict__ icnt,
                                                int* __restrict__ offs,
                                                int* __restrict__ curs,
                                                float* __restrict__ cntf) {
    __shared__ int ps[256];
    const int t = threadIdx.x;
    int c[8]; int s = 0;
    #pragma unroll
    for (int j = 0; j < 8; ++j) c[j] = icnt[t * 8 + j];
    #pragma unroll
    for (int j = 0; j < 8; ++j) { int tmp = c[j]; c[j] = s; s += tmp; }
    ps[t] = s;
    __syncthreads();
    for (int off = 1; off < 256; off <<= 1) {
        int v = (t >= off) ? ps[t - off] : 0;
        __syncthreads();
        ps[t] += v;
        __syncthreads();
    }
    int base = ps[t] - s;
    #pragma unroll
    for (int j = 0; j < 8; ++j) {
        int o = base + c[j];
        offs[t * 8 + j] = o;
        curs[t * 8 + j] = o;
        cntf[t * 8 + j] = (float)(icnt[t * 8 + j]);
    }
}

__global__ __launch_bounds__(256) void k_scatter(const float* __restrict__ out,
                                                 int* __restrict__ curs,
                                                 int* __restrict__ plist) {
    int n = blockIdx.x * 256 + threadIdx.x;
    int id = (int)out[IDS_OFF + n];
    int pos = atomicAdd(&curs[id], 1);
    plist[pos] = n;
}

// one block per code: dense esum + per-code loss term
__global__ __launch_bounds__(256) void k_esum(
    const float* __restrict__ xt, const float* __restrict__ embed,
    const float* __restrict__ norms, const int* __restrict__ offs,
    const int* __restrict__ icnt, const int* __restrict__ plist,
    float* __restrict__ esum, float* __restrict__ lossd)
{
    __shared__ int   ns[256];
    __shared__ float red[256];
    const int d = blockIdx.x;
    const int t = threadIdx.x;
    const int start = offs[d];
    const int cnt   = icnt[d];
    float acc = 0.f;
    for (int base = 0; base < cnt; base += 256) {
        int m = min(256, cnt - base);
        __syncthreads();
        if (t < m) ns[t] = plist[start + base + t];
        __syncthreads();
        #pragma unroll 4
        for (int i = 0; i < m; ++i) {
            acc += xt[(size_t)ns[i] * C_DIM + t];
        }
    }
    esum[(size_t)t * D_CODES + d] = acc;
    float dd = acc * embed[(size_t)d * C_DIM + t];
    red[t] = dd;
    __syncthreads();
    for (int o = 128; o; o >>= 1) {
        if (t < o) red[t] += red[t + o];
        __syncthreads();
    }
    if (t == 0) lossd[d] = 2.f * red[0] - (float)cnt * norms[d];
}

// quantized output via LDS-staged embed rows (overwrites the xt region)
__global__ __launch_bounds__(256) void k_quant(
    const float* __restrict__ embed, float* __restrict__ out)
{
    __shared__ int   ids_s[64];
    __shared__ float es[32][257];
    const int t  = threadIdx.x;
    const int bi = blockIdx.x >> 6;
    const int hi = blockIdx.x & 63;
    const int wl = t & 31;
    const int cg = t >> 5;
    if (t < 64) ids_s[t] = (int)out[IDS_OFF + ((size_t)bi << 12) + (t << 6) + hi];
    __syncthreads();
    #pragma unroll
    for (int pass = 0; pass < 2; ++pass) {
        #pragma unroll 8
        for (int p = 0; p < 32; ++p) {
            es[p][t] = embed[(size_t)ids_s[pass * 32 + p] * C_DIM + t];
        }
        __syncthreads();
        #pragma unroll 8
        for (int k = 0; k < 32; ++k) {
            int ch = k * 8 + cg;
            out[Q_OFF + ((size_t)(bi * C_DIM + ch)) * 4096 + hi * 64 + pass * 32 + wl]
                = es[wl][ch];
        }
        __syncthreads();
    }
}

__global__ __launch_bounds__(256) void k_final_small(
    const float* __restrict__ cs_in, const float* __restrict__ cntf,
    const float* __restrict__ lossd, const float* __restrict__ sumx2p,
    float* __restrict__ out, float* __restrict__ ntot)
{
    __shared__ float sm[256];
    const int t = threadIdx.x;
    float s1 = 0.f;
    for (int i = t; i < 1024; i += 256) s1 += sumx2p[i];
    float s2 = 0.f;
    for (int i = t; i < 2048; i += 256) s2 += lossd[i];
    sm[t] = s1 - s2;
    __syncthreads();
    for (int o = 128; o; o >>= 1) { if (t < o) sm[t] += sm[t + o]; __syncthreads(); }
    if (t == 0) out[LOSS_OFF] = sm[0] / 16777216.f;
    __syncthreads();
    float cs = 0.f;
    for (int i = t; i < D_CODES; i += 256) {
        float v = MOM * cs_in[i] + ONE_M * cntf[i];
        out[NCS_OFF + i] = v;
        cs += v;
    }
    sm[t] = cs; __syncthreads();
    for (int o = 128; o; o >>= 1) { if (t < o) sm[t] += sm[t + o]; __syncthreads(); }
    if (t == 0) *ntot = sm[0];
}

__global__ __launch_bounds__(256) void k_final_embed(
    const float* __restrict__ embed_avg, const float* __restrict__ esum,
    const float* __restrict__ ntotp, float* __restrict__ out)
{
    int b  = blockIdx.x;
    int ch = b >> 3;
    int d  = ((b & 7) << 8) + threadIdx.x;
    float ntot = *ntotp;
    float ncs  = out[NCS_OFF + d];
    float csm  = ntot * (ncs + EPSI) / (ntot + (float)D_CODES * EPSI);
    size_t i = (size_t)ch * D_CODES + d;
    float nea = MOM * embed_avg[i] + ONE_M * esum[i];
    out[NEA_OFF + i] = nea;
    out[NE_OFF + (size_t)d * C_DIM + ch] = nea / csm;
}

extern "C" void kernel_launch(void* const* d_in, const int* in_sizes, int n_in,
                              void* d_out, int out_size, void* d_ws, size_t ws_size,
                              hipStream_t stream) {
    const float* x     = (const float*)d_in[0];
    const float* embed = (const float*)d_in[1];
    const float* cs    = (const float*)d_in[2];
    const float* ea    = (const float*)d_in[3];
    float* out = (float*)d_out;
    float* ws  = (float*)d_ws;
    int*      icnt   = (int*)(ws + WS_ICNT);
    float*    cntf   = ws + WS_CNTF;
    int*      offs   = (int*)(ws + WS_OFFS);
    int*      curs   = (int*)(ws + WS_CURS);
    float*    lossd  = ws + WS_LOSSD;
    float*    sumx2p = ws + WS_SUMX2;
    float*    ntot   = ws + WS_NTOT;
    unsigned* rcnt   = (unsigned*)(ws + WS_RCNT);
    float*    norms  = ws + WS_NORMS;
    int*      rlist  = (int*)(ws + WS_RLIST);
    float*    esum   = ws + WS_ESUM;
    float*    e2     = ws + WS_E2;
    float*    xt     = out + Q_OFF;   // staged in quantized region, overwritten by k_quant
    int*      plist  = rlist;         // reuse: rlist no longer needed after k_rescue? NO —
    // rlist (16384) is too small for plist (65536); use a dedicated region instead:
    // place plist right after e2 (e2 ends at WS_E2 + 524288 = 1078280 floats).
    plist = (int*)(ws + WS_E2 + 524288);

    k_zero<<<8, 256, 0, stream>>>(icnt, rcnt);
    k_norms<<<512, 256, 0, stream>>>(embed, norms);
    k_eprep<<<64, 256, 0, stream>>>(embed, e2);
    k_xt<<<1024, 256, 0, stream>>>(x, xt, sumx2p);
    k_main<<<512, 256, 0, stream>>>(x, e2, norms, out, rcnt, rlist);
    k_rescue<<<128, 256, 0, stream>>>(x, embed, norms, rcnt, rlist, out);
    k_hist<<<256, 256, 0, stream>>>(out, icnt);
    k_prefix<<<1, 256, 0, stream>>>(icnt, offs, curs, cntf);
    k_scatter<<<256, 256, 0, stream>>>(out, curs, plist);
    k_esum<<<2048, 256, 0, stream>>>(xt, embed, norms, offs, icnt, plist, esum, lossd);
    k_quant<<<1024, 256, 0, stream>>>(embed, out);
    k_final_small<<<1, 256, 0, stream>>>(cs, cntf, lossd, sumx2p, out, ntot);
    k_final_embed<<<2048, 256, 0, stream>>>(ea, esum, ntot, out);
}

// Round 4
// 443.314 us; speedup vs baseline: 5.1592x; 1.7337x over previous
//
#include <hip/hip_runtime.h>

#define D_CODES 2048
#define C_DIM   256
#define MOM     0.99f
#define ONE_M   0.01f
#define EPSI    1e-5f
#define TAU     0.0625f
#define RCAP    16384
#define SBCAP   2304

// output offsets (floats)
#define Q_OFF    0
#define LOSS_OFF 16777216
#define IDS_OFF  16777217
#define NE_OFF   16842753
#define NCS_OFF  17367041
#define NEA_OFF  17369089

// workspace offsets (floats)
#define WS_ICNT   0
#define WS_CNTF   2048
#define WS_OFFS   4096
#define WS_CURS   6144
#define WS_SUMX2  10240
#define WS_NTOT   11264
#define WS_RCNT   11268
#define WS_NSB    11269
#define WS_NORMS  11272
#define WS_RLIST  13320
#define WS_ESUM   29704
#define WS_E2     553992
#define WS_PLIST  1078280
#define WS_SBCODE 1143816
#define WS_SBSTART 1146120
#define WS_SBINFO 1148424
#define WS_LOSSP  1150728

typedef __attribute__((ext_vector_type(8))) short short8;
typedef __attribute__((ext_vector_type(4))) float f32x4;

__device__ __forceinline__ unsigned short f2bf(float v) {
    unsigned u = __float_as_uint(v);
    unsigned r = u + 0x7FFFu + ((u >> 16) & 1u);
    return (unsigned short)(r >> 16);
}
__device__ __forceinline__ float bf2f(unsigned short h) {
    return __uint_as_float(((unsigned)h) << 16);
}
__device__ __forceinline__ f32x4 MF(short8 a, short8 b, f32x4 c) {
    return __builtin_amdgcn_mfma_f32_16x16x32_bf16(a, b, c, 0, 0, 0);
}

// grid 2048: zeroes esum (524288), icnt, lossp, rcnt
__global__ __launch_bounds__(256) void k_zero(int* __restrict__ icnt,
                                              unsigned* __restrict__ rcnt,
                                              float* __restrict__ esum,
                                              float* __restrict__ lossp) {
    int i = blockIdx.x * 256 + threadIdx.x;
    if (i < D_CODES) icnt[i] = 0;
    if (i < SBCAP) lossp[i] = 0.f;
    esum[i] = 0.f;
    if (i == 0) *rcnt = 0u;
}

__global__ __launch_bounds__(256) void k_norms(const float* __restrict__ embed,
                                               float* __restrict__ norms) {
    int row  = blockIdx.x * 4 + (threadIdx.x >> 6);
    int lane = threadIdx.x & 63;
    float4 v = *(const float4*)(embed + (size_t)row * C_DIM + lane * 4);
    float s = v.x * v.x + v.y * v.y + v.z * v.z + v.w * v.w;
    #pragma unroll
    for (int o = 32; o; o >>= 1) s += __shfl_down(s, o);
    if (lane == 0) norms[row] = s;
}

// pack embed into MFMA A-fragment order, bf16 hi/lo, 64 stages x 32 codes
__global__ __launch_bounds__(256) void k_eprep(const float* __restrict__ embed,
                                               float* __restrict__ e2f) {
    int s = blockIdx.x, t = threadIdx.x;
    char* e2 = (char*)e2f;
    #pragma unroll
    for (int it = 0; it < 4; ++it) {
        int u = it * 256 + t;
        int r = u >> 9, kc = (u >> 6) & 7, l = u & 63;
        int code = s * 32 + r * 16 + (l & 15);
        int ch0  = kc * 32 + ((l >> 4) << 3);
        const float* src = embed + (size_t)code * C_DIM + ch0;
        float4 v0 = *(const float4*)src;
        float4 v1 = *(const float4*)(src + 4);
        float vv[8] = {v0.x, v0.y, v0.z, v0.w, v1.x, v1.y, v1.z, v1.w};
        short8 hi, lo;
        #pragma unroll
        for (int j = 0; j < 8; ++j) {
            unsigned short h = f2bf(vv[j]);
            hi[j] = (short)h;
            lo[j] = (short)f2bf(vv[j] - bf2f(h));
        }
        char* dst = e2 + (size_t)s * 32768 + (size_t)(((r * 8 + kc) * 2 + 0) * 64 + l) * 16;
        *(short8*)dst = hi;
        *(short8*)(dst + 1024) = lo;
    }
}

// transpose x -> xt[n][ch] (into out's quantized region, overwritten later) + sum x^2
__global__ __launch_bounds__(256) void k_xt(const float* __restrict__ x,
                                            float* __restrict__ xt,
                                            float* __restrict__ sumx2p) {
    __shared__ float xs2[32][257];
    __shared__ float wred[4];
    const int t = threadIdx.x;
    const int bi = blockIdx.x >> 6;
    const int hi = blockIdx.x & 63;
    const int wl = t & 31;
    const int chh = t >> 5;
    float sx2 = 0.f;
    #pragma unroll
    for (int pass = 0; pass < 2; ++pass) {
        __syncthreads();
        #pragma unroll 8
        for (int k = 0; k < 32; ++k) {
            int ch = k * 8 + chh;
            float v = x[((size_t)(bi * C_DIM + ch)) * 4096 + hi * 64 + pass * 32 + wl];
            sx2 += v * v;
            xs2[wl][ch] = v;
        }
        __syncthreads();
        #pragma unroll 8
        for (int j = 0; j < 32; ++j) {
            int wi = pass * 32 + j;
            size_t n = (size_t)bi * 4096 + wi * 64 + hi;
            xt[n * C_DIM + t] = xs2[j][t];
        }
    }
    #pragma unroll
    for (int o = 32; o; o >>= 1) sx2 += __shfl_down(sx2, o);
    __syncthreads();
    if ((t & 63) == 0) wred[t >> 6] = sx2;
    __syncthreads();
    if (t == 0) sumx2p[blockIdx.x] = wred[0] + wred[1] + wred[2] + wred[3];
}

__device__ __forceinline__ void stage_copy(const char* __restrict__ g, char* lds_base,
                                           int w, int l) {
    #pragma unroll
    for (int i = 0; i < 8; ++i) {
        int off = w * 8192 + i * 1024;
        __builtin_amdgcn_global_load_lds(
            (const __attribute__((address_space(1))) void*)(g + off + l * 16),
            (__attribute__((address_space(3))) void*)(lds_base + off),
            16, 0, 0);
    }
}

// MFMA split-bf16 scores + per-pixel argmax (+near-tie flagging)
__global__ __launch_bounds__(256, 2) void k_main(
    const float* __restrict__ x, const float* __restrict__ e2f,
    const float* __restrict__ norms, float* __restrict__ out,
    unsigned* __restrict__ rcnt, int* __restrict__ rlist)
{
    __shared__ char smem[65536];
    const int t  = threadIdx.x;
    const int l  = t & 63;
    const int w  = __builtin_amdgcn_readfirstlane(t >> 6);
    const int bi = blockIdx.x >> 5;
    const int q  = blockIdx.x & 31;
    const char* e2 = (const char*)e2f;

    short8 bxh[2][8], bxl[2][8];
    {
        float* xs = (float*)smem;
        const int hiq = w >> 1;
        const int wib = (w & 1) * 32;
        for (int c = 0; c < 4; ++c) {
            __syncthreads();
            #pragma unroll
            for (int k = 0; k < 8; ++k) {
                int fidx = (k * 256 + t) * 4;
                int chl = fidx >> 7, rem = fidx & 127;
                int hq = rem >> 6, wi0 = rem & 63;
                float4 v = *(const float4*)(x + (((size_t)(bi * C_DIM + c * 64 + chl)) * 64
                                                 + 2 * q + hq) * 64 + wi0);
                *(float4*)&xs[fidx] = v;
            }
            __syncthreads();
            #pragma unroll
            for (int kcl = 0; kcl < 2; ++kcl) {
                #pragma unroll
                for (int nt = 0; nt < 2; ++nt) {
                    short8 hi, lo;
                    #pragma unroll
                    for (int j = 0; j < 8; ++j) {
                        int chl = kcl * 32 + ((l >> 4) << 3) + j;
                        float v = xs[chl * 128 + hiq * 64 + wib + nt * 16 + (l & 15)];
                        unsigned short h = f2bf(v);
                        hi[j] = (short)h;
                        lo[j] = (short)f2bf(v - bf2f(h));
                    }
                    bxh[nt][c * 2 + kcl] = hi;
                    bxl[nt][c * 2 + kcl] = lo;
                }
            }
        }
        __syncthreads();
    }

    float m1[2] = {-3.4e38f, -3.4e38f}, m2[2] = {-3.4e38f, -3.4e38f};
    int   i1[2] = {0, 0};

    stage_copy(e2, smem, w, l);
    __syncthreads();

    for (int s = 0; s < 64; ++s) {
        char* cur = smem + (s & 1) * 32768;
        if (s < 63)
            stage_copy(e2 + (size_t)(s + 1) * 32768, smem + ((s + 1) & 1) * 32768, w, l);

        #pragma unroll
        for (int r = 0; r < 2; ++r) {
            f32x4 z = {0.f, 0.f, 0.f, 0.f};
            f32x4 hh0 = z, hl0 = z, lh0 = z, hh1 = z, hl1 = z, lh1 = z;
            #pragma unroll
            for (int kc = 0; kc < 8; ++kc) {
                short8 ah = *(const short8*)(cur + ((r * 8 + kc) * 2 + 0) * 1024 + l * 16);
                short8 al = *(const short8*)(cur + ((r * 8 + kc) * 2 + 1) * 1024 + l * 16);
                hh0 = MF(ah, bxh[0][kc], hh0);
                hl0 = MF(ah, bxl[0][kc], hl0);
                lh0 = MF(al, bxh[0][kc], lh0);
                hh1 = MF(ah, bxh[1][kc], hh1);
                hl1 = MF(ah, bxl[1][kc], hl1);
                lh1 = MF(al, bxh[1][kc], lh1);
            }
            int c0 = s * 32 + r * 16 + ((l >> 4) << 2);
            float4 nrm = *(const float4*)(norms + c0);
            float nr[4] = {nrm.x, nrm.y, nrm.z, nrm.w};
            #pragma unroll
            for (int reg = 0; reg < 4; ++reg) {
                float s0 = 2.f * (hh0[reg] + hl0[reg] + lh0[reg]) - nr[reg];
                float s1 = 2.f * (hh1[reg] + hl1[reg] + lh1[reg]) - nr[reg];
                int code = c0 + reg;
                if (s0 > m1[0]) { m2[0] = m1[0]; m1[0] = s0; i1[0] = code; }
                else            { m2[0] = fmaxf(m2[0], s0); }
                if (s1 > m1[1]) { m2[1] = m1[1]; m1[1] = s1; i1[1] = code; }
                else            { m2[1] = fmaxf(m2[1], s1); }
            }
        }
        __syncthreads();
    }

    #pragma unroll
    for (int nt = 0; nt < 2; ++nt) {
        float a1 = m1[nt], a2 = m2[nt];
        int   ai = i1[nt];
        #pragma unroll
        for (int off = 16; off <= 32; off <<= 1) {
            float o1 = __shfl_xor(a1, off);
            int   oi = __shfl_xor(ai, off);
            float o2 = __shfl_xor(a2, off);
            if (o1 > a1)       { a2 = fmaxf(a1, o2); a1 = o1; ai = oi; }
            else if (o1 == a1) { if (oi < ai) ai = oi; a2 = a1; }
            else               { a2 = fmaxf(a2, o1); }
        }
        if (l < 16) {
            int wi = (w & 1) * 32 + nt * 16 + l;
            int hi_ = 2 * q + (w >> 1);
            int n = (bi << 12) + (wi << 6) + hi_;
            out[IDS_OFF + n] = (float)ai;
            if (a1 - a2 < TAU) {
                unsigned j = atomicAdd(rcnt, 1u);
                if (j < RCAP) rlist[j] = n;
            }
        }
    }
}

// exact fp32 rescore for flagged near-tie pixels
__global__ __launch_bounds__(256) void k_rescue(
    const float* __restrict__ x, const float* __restrict__ embed,
    const float* __restrict__ norms, const unsigned* __restrict__ rcnt,
    const int* __restrict__ rlist, float* __restrict__ out)
{
    __shared__ float xs_s[256];
    __shared__ float rs[256];
    __shared__ int   ri[256];
    const int t = threadIdx.x;
    int nf = (int)min(*rcnt, (unsigned)RCAP);
    for (int idx = blockIdx.x; idx < nf; idx += gridDim.x) {
        int n = rlist[idx];
        int bi = n >> 12, wi = (n >> 6) & 63, hi = n & 63;
        xs_s[t] = x[(((size_t)(bi * C_DIM + t)) * 64 + hi) * 64 + wi];
        __syncthreads();
        float best = -3.4e38f; int bd = 0;
        for (int d = t; d < D_CODES; d += 256) {
            const float* er = embed + (size_t)d * C_DIM;
            float a0 = 0.f, a1 = 0.f, a2 = 0.f, a3 = 0.f;
            for (int c = 0; c < C_DIM; c += 4) {
                float4 e4 = *(const float4*)(er + c);
                a0 += xs_s[c]     * e4.x;
                a1 += xs_s[c + 1] * e4.y;
                a2 += xs_s[c + 2] * e4.z;
                a3 += xs_s[c + 3] * e4.w;
            }
            float s = 2.f * (a0 + a1 + a2 + a3) - norms[d];
            if (s > best) { best = s; bd = d; }
        }
        rs[t] = best; ri[t] = bd;
        __syncthreads();
        for (int o = 128; o; o >>= 1) {
            if (t < o) {
                if (rs[t + o] > rs[t] || (rs[t + o] == rs[t] && ri[t + o] < ri[t])) {
                    rs[t] = rs[t + o]; ri[t] = ri[t + o];
                }
            }
            __syncthreads();
        }
        if (t == 0) out[IDS_OFF + n] = (float)ri[0];
        __syncthreads();
    }
}

__global__ __launch_bounds__(256) void k_hist(const float* __restrict__ out,
                                              int* __restrict__ icnt) {
    int n = blockIdx.x * 256 + threadIdx.x;
    int id = (int)out[IDS_OFF + n];
    atomicAdd(&icnt[id], 1);
}

// single block: offsets + sub-block table (256-pixel chunks, skew-proof)
__global__ __launch_bounds__(256) void k_prefix(const int* __restrict__ icnt,
                                                int* __restrict__ offs,
                                                int* __restrict__ curs,
                                                float* __restrict__ cntf,
                                                int* __restrict__ sbcode,
                                                int* __restrict__ sbstart,
                                                int* __restrict__ sbinfo,
                                                int* __restrict__ nsbtot) {
    __shared__ int ps[256];
    const int t = threadIdx.x;
    int c[8], o8[8];
    int s = 0;
    #pragma unroll
    for (int j = 0; j < 8; ++j) c[j] = icnt[t * 8 + j];
    #pragma unroll
    for (int j = 0; j < 8; ++j) { int tmp = c[j]; c[j] = s; s += tmp; }
    ps[t] = s;
    __syncthreads();
    for (int off = 1; off < 256; off <<= 1) {
        int v = (t >= off) ? ps[t - off] : 0;
        __syncthreads();
        ps[t] += v;
        __syncthreads();
    }
    int base = ps[t] - s;
    #pragma unroll
    for (int j = 0; j < 8; ++j) {
        int o = base + c[j];
        o8[j] = o;
        offs[t * 8 + j] = o;
        curs[t * 8 + j] = o;
        cntf[t * 8 + j] = (float)(icnt[t * 8 + j]);
    }
    // second scan: sub-block counts
    int s2 = 0;
    int nb[8];
    #pragma unroll
    for (int j = 0; j < 8; ++j) {
        int cnt = icnt[t * 8 + j];
        nb[j] = (cnt + 255) >> 8;
        s2 += nb[j];
    }
    __syncthreads();
    ps[t] = s2;
    __syncthreads();
    for (int off = 1; off < 256; off <<= 1) {
        int v = (t >= off) ? ps[t - off] : 0;
        __syncthreads();
        ps[t] += v;
        __syncthreads();
    }
    int pos = ps[t] - s2;
    #pragma unroll
    for (int j = 0; j < 8; ++j) {
        int code = t * 8 + j;
        int cnt = icnt[code];
        int n = nb[j];
        for (int k = 0; k < n; ++k) {
            sbcode[pos]  = code;
            sbstart[pos] = o8[j] + k * 256;
            int len = cnt - k * 256; if (len > 256) len = 256;
            sbinfo[pos]  = len | ((n > 1) ? (1 << 16) : 0);
            ++pos;
        }
    }
    if (t == 255) *nsbtot = ps[255];
}

__global__ __launch_bounds__(256) void k_scatter(const float* __restrict__ out,
                                                 int* __restrict__ curs,
                                                 int* __restrict__ plist) {
    int n = blockIdx.x * 256 + threadIdx.x;
    int id = (int)out[IDS_OFF + n];
    int pos = atomicAdd(&curs[id], 1);
    plist[pos] = n;
}

// grid-stride over sub-blocks: dense esum partials + per-sub-block loss term
__global__ __launch_bounds__(256) void k_esum(
    const float* __restrict__ xt, const float* __restrict__ embed,
    const float* __restrict__ norms, const int* __restrict__ sbcode,
    const int* __restrict__ sbstart, const int* __restrict__ sbinfo,
    const int* __restrict__ plist, const int* __restrict__ nsbtot,
    float* __restrict__ esum, float* __restrict__ lossp)
{
    __shared__ int   ns[256];
    __shared__ float red[256];
    const int t = threadIdx.x;
    const int total = *nsbtot;
    for (int sb = blockIdx.x; sb < total; sb += gridDim.x) {
        const int d     = sbcode[sb];
        const int start = sbstart[sb];
        const int info  = sbinfo[sb];
        const int len   = info & 0xFFFF;
        const bool multi = (info >> 16) != 0;
        __syncthreads();
        if (t < len) ns[t] = plist[start + t];
        __syncthreads();
        float acc = 0.f;
        #pragma unroll 8
        for (int i = 0; i < len; ++i)
            acc += xt[(size_t)ns[i] * C_DIM + t];
        if (multi) atomicAdd(&esum[(size_t)t * D_CODES + d], acc);
        else       esum[(size_t)t * D_CODES + d] = acc;
        red[t] = acc * embed[(size_t)d * C_DIM + t];
        __syncthreads();
        for (int o = 128; o; o >>= 1) {
            if (t < o) red[t] += red[t + o];
            __syncthreads();
        }
        if (t == 0) lossp[sb] = 2.f * red[0] - (float)len * norms[d];
    }
}

// quantized output via LDS-staged embed rows (overwrites the xt region)
__global__ __launch_bounds__(256) void k_quant(
    const float* __restrict__ embed, float* __restrict__ out)
{
    __shared__ int   ids_s[64];
    __shared__ float es[32][257];
    const int t  = threadIdx.x;
    const int bi = blockIdx.x >> 6;
    const int hi = blockIdx.x & 63;
    const int wl = t & 31;
    const int cg = t >> 5;
    if (t < 64) ids_s[t] = (int)out[IDS_OFF + ((size_t)bi << 12) + (t << 6) + hi];
    __syncthreads();
    #pragma unroll
    for (int pass = 0; pass < 2; ++pass) {
        #pragma unroll 8
        for (int p = 0; p < 32; ++p) {
            es[p][t] = embed[(size_t)ids_s[pass * 32 + p] * C_DIM + t];
        }
        __syncthreads();
        #pragma unroll 8
        for (int k = 0; k < 32; ++k) {
            int ch = k * 8 + cg;
            out[Q_OFF + ((size_t)(bi * C_DIM + ch)) * 4096 + hi * 64 + pass * 32 + wl]
                = es[wl][ch];
        }
        __syncthreads();
    }
}

__global__ __launch_bounds__(256) void k_final_small(
    const float* __restrict__ cs_in, const float* __restrict__ cntf,
    const float* __restrict__ lossp, const float* __restrict__ sumx2p,
    float* __restrict__ out, float* __restrict__ ntot)
{
    __shared__ float sm[256];
    const int t = threadIdx.x;
    float s1 = 0.f;
    for (int i = t; i < 1024; i += 256) s1 += sumx2p[i];
    float s2 = 0.f;
    for (int i = t; i < SBCAP; i += 256) s2 += lossp[i];
    sm[t] = s1 - s2;
    __syncthreads();
    for (int o = 128; o; o >>= 1) { if (t < o) sm[t] += sm[t + o]; __syncthreads(); }
    if (t == 0) out[LOSS_OFF] = sm[0] / 16777216.f;
    __syncthreads();
    float cs = 0.f;
    for (int i = t; i < D_CODES; i += 256) {
        float v = MOM * cs_in[i] + ONE_M * cntf[i];
        out[NCS_OFF + i] = v;
        cs += v;
    }
    sm[t] = cs; __syncthreads();
    for (int o = 128; o; o >>= 1) { if (t < o) sm[t] += sm[t + o]; __syncthreads(); }
    if (t == 0) *ntot = sm[0];
}

__global__ __launch_bounds__(256) void k_final_embed(
    const float* __restrict__ embed_avg, const float* __restrict__ esum,
    const float* __restrict__ ntotp, float* __restrict__ out)
{
    int b  = blockIdx.x;
    int ch = b >> 3;
    int d  = ((b & 7) << 8) + threadIdx.x;
    float ntot = *ntotp;
    float ncs  = out[NCS_OFF + d];
    float csm  = ntot * (ncs + EPSI) / (ntot + (float)D_CODES * EPSI);
    size_t i = (size_t)ch * D_CODES + d;
    float nea = MOM * embed_avg[i] + ONE_M * esum[i];
    out[NEA_OFF + i] = nea;
    out[NE_OFF + (size_t)d * C_DIM + ch] = nea / csm;
}

extern "C" void kernel_launch(void* const* d_in, const int* in_sizes, int n_in,
                              void* d_out, int out_size, void* d_ws, size_t ws_size,
                              hipStream_t stream) {
    const float* x     = (const float*)d_in[0];
    const float* embed = (const float*)d_in[1];
    const float* cs    = (const float*)d_in[2];
    const float* ea    = (const float*)d_in[3];
    float* out = (float*)d_out;
    float* ws  = (float*)d_ws;
    int*      icnt    = (int*)(ws + WS_ICNT);
    float*    cntf    = ws + WS_CNTF;
    int*      offs    = (int*)(ws + WS_OFFS);
    int*      curs    = (int*)(ws + WS_CURS);
    float*    sumx2p  = ws + WS_SUMX2;
    float*    ntot    = ws + WS_NTOT;
    unsigned* rcnt    = (unsigned*)(ws + WS_RCNT);
    int*      nsbtot  = (int*)(ws + WS_NSB);
    float*    norms   = ws + WS_NORMS;
    int*      rlist   = (int*)(ws + WS_RLIST);
    float*    esum    = ws + WS_ESUM;
    float*    e2      = ws + WS_E2;
    int*      plist   = (int*)(ws + WS_PLIST);
    int*      sbcode  = (int*)(ws + WS_SBCODE);
    int*      sbstart = (int*)(ws + WS_SBSTART);
    int*      sbinfo  = (int*)(ws + WS_SBINFO);
    float*    lossp   = ws + WS_LOSSP;
    float*    xt      = out + Q_OFF;   // staged in quantized region, overwritten by k_quant

    k_zero<<<2048, 256, 0, stream>>>(icnt, rcnt, esum, lossp);
    k_norms<<<512, 256, 0, stream>>>(embed, norms);
    k_eprep<<<64, 256, 0, stream>>>(embed, e2);
    k_xt<<<1024, 256, 0, stream>>>(x, xt, sumx2p);
    k_main<<<512, 256, 0, stream>>>(x, e2, norms, out, rcnt, rlist);
    k_rescue<<<256, 256, 0, stream>>>(x, embed, norms, rcnt, rlist, out);
    k_hist<<<256, 256, 0, stream>>>(out, icnt);
    k_prefix<<<1, 256, 0, stream>>>(icnt, offs, curs, cntf, sbcode, sbstart, sbinfo, nsbtot);
    k_scatter<<<256, 256, 0, stream>>>(out, curs, plist);
    k_esum<<<SBCAP, 256, 0, stream>>>(xt, embed, norms, sbcode, sbstart, sbinfo,
                                      plist, nsbtot, esum, lossp);
    k_quant<<<1024, 256, 0, stream>>>(embed, out);
    k_final_small<<<1, 256, 0, stream>>>(cs, cntf, lossp, sumx2p, out, ntot);
    k_final_embed<<<2048, 256, 0, stream>>>(ea, esum, ntot, out);
}

// Round 5
// 351.164 us; speedup vs baseline: 6.5131x; 1.2624x over previous
//
#include <hip/hip_runtime.h>

#define D_CODES 2048
#define C_DIM   256
#define MOM     0.99f
#define ONE_M   0.01f
#define EPSI    1e-5f
#define TAU     0.15f
#define RCAP    16384
#define SBCAP   2304

// output offsets (floats)
#define Q_OFF    0
#define LOSS_OFF 16777216
#define IDS_OFF  16777217
#define NE_OFF   16842753
#define NCS_OFF  17367041
#define NEA_OFF  17369089

// workspace offsets (floats)
#define WS_ICNT   0
#define WS_CNTF   2048
#define WS_OFFS   4096
#define WS_CURS   6144
#define WS_SUMX2  10240
#define WS_NTOT   11264
#define WS_RCNT   11268
#define WS_NSB    11269
#define WS_NORMS  11272
#define WS_RLIST  13320
#define WS_ESUM   29704
#define WS_E2     553992
#define WS_KEYS   816136
#define WS_PLIST  1078280
#define WS_SBCODE 1143816
#define WS_SBSTART 1146120
#define WS_SBINFO 1148424
#define WS_LOSSP  1150728

typedef _Float16 half8 __attribute__((ext_vector_type(8)));
typedef __attribute__((ext_vector_type(4))) float f32x4;

__device__ __forceinline__ f32x4 MFH(half8 a, half8 b, f32x4 c) {
    return __builtin_amdgcn_mfma_f32_16x16x32_f16(a, b, c, 0, 0, 0);
}

// grid 2048: zeroes esum (524288), icnt, lossp, rcnt
__global__ __launch_bounds__(256) void k_zero(int* __restrict__ icnt,
                                              unsigned* __restrict__ rcnt,
                                              float* __restrict__ esum,
                                              float* __restrict__ lossp) {
    int i = blockIdx.x * 256 + threadIdx.x;
    if (i < D_CODES) icnt[i] = 0;
    if (i < SBCAP) lossp[i] = 0.f;
    esum[i] = 0.f;
    if (i == 0) *rcnt = 0u;
}

__global__ __launch_bounds__(256) void k_norms(const float* __restrict__ embed,
                                               float* __restrict__ norms) {
    int row  = blockIdx.x * 4 + (threadIdx.x >> 6);
    int lane = threadIdx.x & 63;
    float4 v = *(const float4*)(embed + (size_t)row * C_DIM + lane * 4);
    float s = v.x * v.x + v.y * v.y + v.z * v.z + v.w * v.w;
    #pragma unroll
    for (int o = 32; o; o >>= 1) s += __shfl_down(s, o);
    if (lane == 0) norms[row] = s;
}

// pack embed into MFMA A-fragment order, fp16, 64 stages x 32 codes (16KB/stage)
__global__ __launch_bounds__(256) void k_eprep(const float* __restrict__ embed,
                                               float* __restrict__ e2f) {
    int s = blockIdx.x, t = threadIdx.x;
    char* e2 = (char*)e2f;
    #pragma unroll
    for (int it = 0; it < 4; ++it) {
        int u = it * 256 + t;
        int r = u >> 9, kc = (u >> 6) & 7, l = u & 63;
        int code = s * 32 + r * 16 + (l & 15);
        int ch0  = kc * 32 + ((l >> 4) << 3);
        const float* src = embed + (size_t)code * C_DIM + ch0;
        float4 v0 = *(const float4*)src;
        float4 v1 = *(const float4*)(src + 4);
        float vv[8] = {v0.x, v0.y, v0.z, v0.w, v1.x, v1.y, v1.z, v1.w};
        half8 hh;
        #pragma unroll
        for (int j = 0; j < 8; ++j) hh[j] = (_Float16)vv[j];
        char* dst = e2 + (size_t)s * 16384 + (size_t)((r * 8 + kc) * 64 + l) * 16;
        *(half8*)dst = hh;
    }
}

__device__ __forceinline__ void stage_copy(const char* __restrict__ g, char* lds_base,
                                           int w, int l) {
    #pragma unroll
    for (int i = 0; i < 4; ++i) {
        int off = w * 4096 + i * 1024;
        __builtin_amdgcn_global_load_lds(
            (const __attribute__((address_space(1))) void*)(g + off + l * 16),
            (__attribute__((address_space(3))) void*)(lds_base + off),
            16, 0, 0);
    }
}

// MFMA fp16 2-product scores + argmax + xt transpose + sumx2 (+near-tie flagging)
__global__ __launch_bounds__(256, 2) void k_main(
    const float* __restrict__ x, const float* __restrict__ e2f,
    const float* __restrict__ norms, float* __restrict__ out,
    float* __restrict__ xt, float* __restrict__ sumx2p,
    unsigned* __restrict__ rcnt, int* __restrict__ rlist,
    unsigned long long* __restrict__ keys)
{
    __shared__ char smem[34816];      // prologue: xs[128][68] f32; main: 2x16KB stages
    __shared__ float wred[4];
    const int t  = threadIdx.x;
    const int l  = t & 63;
    const int w  = __builtin_amdgcn_readfirstlane(t >> 6);
    const int bi = blockIdx.x >> 5;
    const int q  = blockIdx.x & 31;
    const char* e2 = (const char*)e2f;

    half8 bxh[2][8], bxl[2][8];
    float sx2 = 0.f;
    {
        float* xs = (float*)smem;     // [pl 128][68]
        const int hiq = w >> 1;
        const int wib = (w & 1) * 32;
        for (int c = 0; c < 4; ++c) {
            __syncthreads();
            #pragma unroll
            for (int k = 0; k < 8; ++k) {
                int u = k * 256 + t;
                int wi0 = (u & 15) * 4;
                int hq  = (u >> 4) & 1;
                int chl = u >> 5;
                float4 v = *(const float4*)(x + ((size_t)(bi * C_DIM + c * 64 + chl)) * 4096
                                              + (2 * q + hq) * 64 + wi0);
                int pb = (hq * 64 + wi0) * 68 + chl;
                xs[pb] = v.x; xs[pb + 68] = v.y; xs[pb + 136] = v.z; xs[pb + 204] = v.w;
            }
            __syncthreads();
            // xt write (transposed, coalesced 256B chunks) + sumx2
            {
                int plo = t >> 4;
                int cc4 = (t & 15) * 4;
                #pragma unroll
                for (int p8 = 0; p8 < 8; ++p8) {
                    int pl = p8 * 16 + plo;
                    float4 f = *(const float4*)&xs[pl * 68 + cc4];
                    int hq = pl >> 6, wi = pl & 63;
                    size_t n = (size_t)bi * 4096 + (size_t)wi * 64 + (2 * q + hq);
                    *(float4*)(xt + n * C_DIM + c * 64 + cc4) = f;
                    sx2 += f.x * f.x + f.y * f.y + f.z * f.z + f.w * f.w;
                }
            }
            // x B-fragments: fp16 hi + fp16 residual
            #pragma unroll
            for (int kcl = 0; kcl < 2; ++kcl) {
                #pragma unroll
                for (int nt = 0; nt < 2; ++nt) {
                    int pl = hiq * 64 + wib + nt * 16 + (l & 15);
                    const float* src = &xs[pl * 68 + kcl * 32 + ((l >> 4) << 3)];
                    float4 f0 = *(const float4*)src;
                    float4 f1 = *(const float4*)(src + 4);
                    float vv[8] = {f0.x, f0.y, f0.z, f0.w, f1.x, f1.y, f1.z, f1.w};
                    half8 hh, rr;
                    #pragma unroll
                    for (int j = 0; j < 8; ++j) {
                        _Float16 h = (_Float16)vv[j];
                        hh[j] = h;
                        rr[j] = (_Float16)(vv[j] - (float)h);
                    }
                    bxh[nt][c * 2 + kcl] = hh;
                    bxl[nt][c * 2 + kcl] = rr;
                }
            }
        }
        __syncthreads();
    }
    #pragma unroll
    for (int o = 32; o; o >>= 1) sx2 += __shfl_down(sx2, o);
    if (l == 0) wred[w] = sx2;

    float m1[2] = {-3.4e38f, -3.4e38f}, m2[2] = {-3.4e38f, -3.4e38f};
    int   i1[2] = {0, 0};

    stage_copy(e2, smem, w, l);
    __syncthreads();

    for (int s = 0; s < 64; ++s) {
        char* cur = smem + (s & 1) * 16384;
        if (s < 63)
            stage_copy(e2 + (size_t)(s + 1) * 16384, smem + ((s + 1) & 1) * 16384, w, l);

        #pragma unroll
        for (int r = 0; r < 2; ++r) {
            f32x4 z = {0.f, 0.f, 0.f, 0.f};
            f32x4 aA0 = z, aL0 = z, aA1 = z, aL1 = z;
            #pragma unroll
            for (int kc = 0; kc < 8; ++kc) {
                half8 ah = *(const half8*)(cur + ((r * 8 + kc) * 64 + l) * 16);
                aA0 = MFH(ah, bxh[0][kc], aA0);
                aL0 = MFH(ah, bxl[0][kc], aL0);
                aA1 = MFH(ah, bxh[1][kc], aA1);
                aL1 = MFH(ah, bxl[1][kc], aL1);
            }
            int c0 = s * 32 + r * 16 + ((l >> 4) << 2);
            float4 nrm = *(const float4*)(norms + c0);
            float nr[4] = {nrm.x, nrm.y, nrm.z, nrm.w};
            #pragma unroll
            for (int reg = 0; reg < 4; ++reg) {
                float s0 = 2.f * (aA0[reg] + aL0[reg]) - nr[reg];
                float s1 = 2.f * (aA1[reg] + aL1[reg]) - nr[reg];
                int code = c0 + reg;
                if (s0 > m1[0]) { m2[0] = m1[0]; m1[0] = s0; i1[0] = code; }
                else            { m2[0] = fmaxf(m2[0], s0); }
                if (s1 > m1[1]) { m2[1] = m1[1]; m1[1] = s1; i1[1] = code; }
                else            { m2[1] = fmaxf(m2[1], s1); }
            }
        }
        __syncthreads();
    }

    #pragma unroll
    for (int nt = 0; nt < 2; ++nt) {
        float a1 = m1[nt], a2 = m2[nt];
        int   ai = i1[nt];
        #pragma unroll
        for (int off = 16; off <= 32; off <<= 1) {
            float o1 = __shfl_xor(a1, off);
            int   oi = __shfl_xor(ai, off);
            float o2 = __shfl_xor(a2, off);
            if (o1 > a1)       { a2 = fmaxf(a1, o2); a1 = o1; ai = oi; }
            else if (o1 == a1) { if (oi < ai) ai = oi; a2 = a1; }
            else               { a2 = fmaxf(a2, o1); }
        }
        if (l < 16) {
            int wi = (w & 1) * 32 + nt * 16 + l;
            int hi_ = 2 * q + (w >> 1);
            int n = (bi << 12) + (wi << 6) + hi_;
            out[IDS_OFF + n] = (float)ai;
            if (a1 - a2 < TAU) {
                keys[n] = 0ull;
                unsigned j = atomicAdd(rcnt, 1u);
                if (j < RCAP) rlist[j] = n;
            }
        }
    }
    __syncthreads();
    if (t == 0) sumx2p[blockIdx.x] = wred[0] + wred[1] + wred[2] + wred[3];
}

// exact fp32 rescore: 16-pixel chunks x 4 code-slabs, packed-key atomicMax merge
__global__ __launch_bounds__(256) void k_rescue(
    const float* __restrict__ x, const float* __restrict__ embed,
    const float* __restrict__ norms, const unsigned* __restrict__ rcnt,
    const int* __restrict__ rlist, unsigned long long* __restrict__ keys)
{
    __shared__ float xs[16][260];
    __shared__ int nn[16];
    const int t = threadIdx.x;
    const int l = t & 63;
    int nf = (int)min(*rcnt, (unsigned)RCAP);
    int nch = (nf + 15) >> 4;
    int njobs = nch * 4;
    for (int job = blockIdx.x; job < njobs; job += gridDim.x) {
        int chunk = job >> 2, slab = job & 3;
        int m = nf - chunk * 16; if (m > 16) m = 16;
        __syncthreads();
        if (t < 16) nn[t] = rlist[chunk * 16 + ((t < m) ? t : 0)];
        __syncthreads();
        #pragma unroll 4
        for (int p = 0; p < 16; ++p) {
            int n = nn[p];
            int bi = n >> 12, wi = (n >> 6) & 63, hi = n & 63;
            xs[p][t] = x[((size_t)(bi * C_DIM + t)) * 4096 + hi * 64 + wi];
        }
        __syncthreads();
        unsigned long long bk[16];
        #pragma unroll
        for (int p = 0; p < 16; ++p) bk[p] = 0ull;
        #pragma unroll
        for (int rep = 0; rep < 2; ++rep) {
            int d = slab * 512 + rep * 256 + t;
            const float* er = embed + (size_t)d * C_DIM;
            float acc[16];
            #pragma unroll
            for (int p = 0; p < 16; ++p) acc[p] = 0.f;
            for (int c = 0; c < C_DIM; c += 4) {
                float4 e4 = *(const float4*)(er + c);
                #pragma unroll
                for (int p = 0; p < 16; ++p) {
                    float4 xv = *(const float4*)&xs[p][c];
                    acc[p] += xv.x * e4.x + xv.y * e4.y + xv.z * e4.z + xv.w * e4.w;
                }
            }
            float nrm = norms[d];
            #pragma unroll
            for (int p = 0; p < 16; ++p) {
                float sc = 2.f * acc[p] - nrm;
                unsigned u = __float_as_uint(sc);
                u = (u & 0x80000000u) ? ~u : (u | 0x80000000u);
                unsigned long long key = ((unsigned long long)u << 32) | (unsigned)(~d);
                if (key > bk[p]) bk[p] = key;
            }
        }
        #pragma unroll
        for (int p = 0; p < 16; ++p) {
            unsigned long long k0 = bk[p];
            #pragma unroll
            for (int o = 32; o; o >>= 1) {
                unsigned long long ok = __shfl_down(k0, o);
                if (ok > k0) k0 = ok;
            }
            if (l == 0) atomicMax(&keys[nn[p]], k0);
        }
    }
}

__global__ __launch_bounds__(256) void k_rescue_fin(
    const unsigned* __restrict__ rcnt, const int* __restrict__ rlist,
    const unsigned long long* __restrict__ keys, float* __restrict__ out)
{
    int i = blockIdx.x * 256 + threadIdx.x;
    int nf = (int)min(*rcnt, (unsigned)RCAP);
    if (i < nf) {
        int n = rlist[i];
        unsigned dlow = (unsigned)(keys[n] & 0xFFFFFFFFull);
        out[IDS_OFF + n] = (float)(~dlow);
    }
}

__global__ __launch_bounds__(256) void k_hist(const float* __restrict__ out,
                                              int* __restrict__ icnt) {
    int n = blockIdx.x * 256 + threadIdx.x;
    int id = (int)out[IDS_OFF + n];
    atomicAdd(&icnt[id], 1);
}

// single block: offsets + sub-block table (256-pixel chunks, skew-proof)
__global__ __launch_bounds__(256) void k_prefix(const int* __restrict__ icnt,
                                                int* __restrict__ offs,
                                                int* __restrict__ curs,
                                                float* __restrict__ cntf,
                                                int* __restrict__ sbcode,
                                                int* __restrict__ sbstart,
                                                int* __restrict__ sbinfo,
                                                int* __restrict__ nsbtot) {
    __shared__ int ps[256];
    const int t = threadIdx.x;
    int c[8], o8[8];
    int s = 0;
    #pragma unroll
    for (int j = 0; j < 8; ++j) c[j] = icnt[t * 8 + j];
    #pragma unroll
    for (int j = 0; j < 8; ++j) { int tmp = c[j]; c[j] = s; s += tmp; }
    ps[t] = s;
    __syncthreads();
    for (int off = 1; off < 256; off <<= 1) {
        int v = (t >= off) ? ps[t - off] : 0;
        __syncthreads();
        ps[t] += v;
        __syncthreads();
    }
    int base = ps[t] - s;
    #pragma unroll
    for (int j = 0; j < 8; ++j) {
        int o = base + c[j];
        o8[j] = o;
        offs[t * 8 + j] = o;
        curs[t * 8 + j] = o;
        cntf[t * 8 + j] = (float)(icnt[t * 8 + j]);
    }
    int s2 = 0;
    int nb[8];
    #pragma unroll
    for (int j = 0; j < 8; ++j) {
        int cnt = icnt[t * 8 + j];
        nb[j] = (cnt + 255) >> 8;
        s2 += nb[j];
    }
    __syncthreads();
    ps[t] = s2;
    __syncthreads();
    for (int off = 1; off < 256; off <<= 1) {
        int v = (t >= off) ? ps[t - off] : 0;
        __syncthreads();
        ps[t] += v;
        __syncthreads();
    }
    int pos = ps[t] - s2;
    #pragma unroll
    for (int j = 0; j < 8; ++j) {
        int code = t * 8 + j;
        int cnt = icnt[code];
        int n = nb[j];
        for (int k = 0; k < n; ++k) {
            sbcode[pos]  = code;
            sbstart[pos] = o8[j] + k * 256;
            int len = cnt - k * 256; if (len > 256) len = 256;
            sbinfo[pos]  = len | ((n > 1) ? (1 << 16) : 0);
            ++pos;
        }
    }
    if (t == 255) *nsbtot = ps[255];
}

__global__ __launch_bounds__(256) void k_scatter(const float* __restrict__ out,
                                                 int* __restrict__ curs,
                                                 int* __restrict__ plist) {
    int n = blockIdx.x * 256 + threadIdx.x;
    int id = (int)out[IDS_OFF + n];
    int pos = atomicAdd(&curs[id], 1);
    plist[pos] = n;
}

// grid-stride over sub-blocks: dense esum partials + per-sub-block loss term
__global__ __launch_bounds__(256) void k_esum(
    const float* __restrict__ xt, const float* __restrict__ embed,
    const float* __restrict__ norms, const int* __restrict__ sbcode,
    const int* __restrict__ sbstart, const int* __restrict__ sbinfo,
    const int* __restrict__ plist, const int* __restrict__ nsbtot,
    float* __restrict__ esum, float* __restrict__ lossp)
{
    __shared__ int   ns[256];
    __shared__ float red[256];
    const int t = threadIdx.x;
    const int total = *nsbtot;
    for (int sb = blockIdx.x; sb < total; sb += gridDim.x) {
        const int d     = sbcode[sb];
        const int start = sbstart[sb];
        const int info  = sbinfo[sb];
        const int len   = info & 0xFFFF;
        const bool multi = (info >> 16) != 0;
        __syncthreads();
        if (t < len) ns[t] = plist[start + t];
        __syncthreads();
        float acc = 0.f;
        #pragma unroll 8
        for (int i = 0; i < len; ++i)
            acc += xt[(size_t)ns[i] * C_DIM + t];
        if (multi) atomicAdd(&esum[(size_t)t * D_CODES + d], acc);
        else       esum[(size_t)t * D_CODES + d] = acc;
        red[t] = acc * embed[(size_t)d * C_DIM + t];
        __syncthreads();
        for (int o = 128; o; o >>= 1) {
            if (t < o) red[t] += red[t + o];
            __syncthreads();
        }
        if (t == 0) lossp[sb] = 2.f * red[0] - (float)len * norms[d];
    }
}

// quantized output via LDS-staged embed rows (overwrites the xt region)
__global__ __launch_bounds__(256) void k_quant(
    const float* __restrict__ embed, float* __restrict__ out)
{
    __shared__ int   ids_s[64];
    __shared__ float es[32][257];
    const int t  = threadIdx.x;
    const int bi = blockIdx.x >> 6;
    const int hi = blockIdx.x & 63;
    const int wl = t & 31;
    const int cg = t >> 5;
    if (t < 64) ids_s[t] = (int)out[IDS_OFF + ((size_t)bi << 12) + (t << 6) + hi];
    __syncthreads();
    #pragma unroll
    for (int pass = 0; pass < 2; ++pass) {
        #pragma unroll 8
        for (int p = 0; p < 32; ++p) {
            es[p][t] = embed[(size_t)ids_s[pass * 32 + p] * C_DIM + t];
        }
        __syncthreads();
        #pragma unroll 8
        for (int k = 0; k < 32; ++k) {
            int ch = k * 8 + cg;
            out[Q_OFF + ((size_t)(bi * C_DIM + ch)) * 4096 + hi * 64 + pass * 32 + wl]
                = es[wl][ch];
        }
        __syncthreads();
    }
}

__global__ __launch_bounds__(256) void k_final_small(
    const float* __restrict__ cs_in, const float* __restrict__ cntf,
    const float* __restrict__ lossp, const float* __restrict__ sumx2p,
    float* __restrict__ out, float* __restrict__ ntot)
{
    __shared__ float sm[256];
    const int t = threadIdx.x;
    float s1 = 0.f;
    for (int i = t; i < 512; i += 256) s1 += sumx2p[i];
    float s2 = 0.f;
    for (int i = t; i < SBCAP; i += 256) s2 += lossp[i];
    sm[t] = s1 - s2;
    __syncthreads();
    for (int o = 128; o; o >>= 1) { if (t < o) sm[t] += sm[t + o]; __syncthreads(); }
    if (t == 0) out[LOSS_OFF] = sm[0] / 16777216.f;
    __syncthreads();
    float cs = 0.f;
    for (int i = t; i < D_CODES; i += 256) {
        float v = MOM * cs_in[i] + ONE_M * cntf[i];
        out[NCS_OFF + i] = v;
        cs += v;
    }
    sm[t] = cs; __syncthreads();
    for (int o = 128; o; o >>= 1) { if (t < o) sm[t] += sm[t + o]; __syncthreads(); }
    if (t == 0) *ntot = sm[0];
}

__global__ __launch_bounds__(256) void k_final_embed(
    const float* __restrict__ embed_avg, const float* __restrict__ esum,
    const float* __restrict__ ntotp, float* __restrict__ out)
{
    int b  = blockIdx.x;
    int ch = b >> 3;
    int d  = ((b & 7) << 8) + threadIdx.x;
    float ntot = *ntotp;
    float ncs  = out[NCS_OFF + d];
    float csm  = ntot * (ncs + EPSI) / (ntot + (float)D_CODES * EPSI);
    size_t i = (size_t)ch * D_CODES + d;
    float nea = MOM * embed_avg[i] + ONE_M * esum[i];
    out[NEA_OFF + i] = nea;
    out[NE_OFF + (size_t)d * C_DIM + ch] = nea / csm;
}

extern "C" void kernel_launch(void* const* d_in, const int* in_sizes, int n_in,
                              void* d_out, int out_size, void* d_ws, size_t ws_size,
                              hipStream_t stream) {
    const float* x     = (const float*)d_in[0];
    const float* embed = (const float*)d_in[1];
    const float* cs    = (const float*)d_in[2];
    const float* ea    = (const float*)d_in[3];
    float* out = (float*)d_out;
    float* ws  = (float*)d_ws;
    int*      icnt    = (int*)(ws + WS_ICNT);
    float*    cntf    = ws + WS_CNTF;
    int*      offs    = (int*)(ws + WS_OFFS);
    int*      curs    = (int*)(ws + WS_CURS);
    float*    sumx2p  = ws + WS_SUMX2;
    float*    ntot    = ws + WS_NTOT;
    unsigned* rcnt    = (unsigned*)(ws + WS_RCNT);
    int*      nsbtot  = (int*)(ws + WS_NSB);
    float*    norms   = ws + WS_NORMS;
    int*      rlist   = (int*)(ws + WS_RLIST);
    float*    esum    = ws + WS_ESUM;
    float*    e2      = ws + WS_E2;
    unsigned long long* keys = (unsigned long long*)(ws + WS_KEYS);
    int*      plist   = (int*)(ws + WS_PLIST);
    int*      sbcode  = (int*)(ws + WS_SBCODE);
    int*      sbstart = (int*)(ws + WS_SBSTART);
    int*      sbinfo  = (int*)(ws + WS_SBINFO);
    float*    lossp   = ws + WS_LOSSP;
    float*    xt      = out + Q_OFF;   // staged in quantized region, overwritten by k_quant

    k_zero<<<2048, 256, 0, stream>>>(icnt, rcnt, esum, lossp);
    k_norms<<<512, 256, 0, stream>>>(embed, norms);
    k_eprep<<<64, 256, 0, stream>>>(embed, e2);
    k_main<<<512, 256, 0, stream>>>(x, e2, norms, out, xt, sumx2p, rcnt, rlist, keys);
    k_rescue<<<1024, 256, 0, stream>>>(x, embed, norms, rcnt, rlist, keys);
    k_rescue_fin<<<64, 256, 0, stream>>>(rcnt, rlist, keys, out);
    k_hist<<<256, 256, 0, stream>>>(out, icnt);
    k_prefix<<<1, 256, 0, stream>>>(icnt, offs, curs, cntf, sbcode, sbstart, sbinfo, nsbtot);
    k_scatter<<<256, 256, 0, stream>>>(out, curs, plist);
    k_esum<<<SBCAP, 256, 0, stream>>>(xt, embed, norms, sbcode, sbstart, sbinfo,
                                      plist, nsbtot, esum, lossp);
    k_quant<<<1024, 256, 0, stream>>>(embed, out);
    k_final_small<<<1, 256, 0, stream>>>(cs, cntf, lossp, sumx2p, out, ntot);
    k_final_embed<<<2048, 256, 0, stream>>>(ea, esum, ntot, out);
}